// Round 4
// baseline (378.189 us; speedup 1.0000x reference)
//
#include <hip/hip_runtime.h>

typedef __bf16 bf16;
typedef __bf16 bf16x8 __attribute__((ext_vector_type(8)));
typedef float f32x4 __attribute__((ext_vector_type(4)));

#define M_TOT 4096
#define D_IN  784
#define HALF  392
#define MID   1000
#define K0PAD 448   // 392 -> mult of 64
#define NPAD  1024  // 1000 padded
#define NBLK  256   // persistent grid size (must equal mlp_k gridDim)

// workspace offsets (bytes)
#define OFF_A0  0            // 4096 x 448  bf16
#define OFF_H0  3670016      // 4096 x 1024 bf16
#define OFF_H1  12058624     // 4096 x 1024 bf16
#define OFF_WT0 20447232     // 1024 x 448  bf16
#define OFF_WTH 21364736     // 4 x 1024 x 1024 bf16
#define OFF_WT5 29753344     // 512 x 1024  bf16
#define OFF_CNT 30801920     // 8 x u32 barrier counters (zeroed by prep_k each launch)

// ---------- async global->LDS 16B ----------
__device__ __forceinline__ void g2l16(const bf16* g, bf16* l) {
  __builtin_amdgcn_global_load_lds(
      (__attribute__((address_space(1))) void*)(g),
      (__attribute__((address_space(3))) void*)(l),
      16, 0, 0);
}

// ---------- 32x32 weight-transpose tile: W (KxN f32) -> WT (Npad x Kpad bf16) ----------
__device__ __forceinline__ void wtrans_tile(const float* __restrict__ W, bf16* __restrict__ WT,
                                            int K, int N, int Kpad, int tn, int tk,
                                            float (*tb)[33], int tid) {
  int n0 = tn * 32, k0 = tk * 32;
  int tx = tid & 31, ty = tid >> 5;
#pragma unroll
  for (int r = 0; r < 4; ++r) {
    int k = k0 + ty + 8 * r, n = n0 + tx;
    tb[ty + 8 * r][tx] = (k < K && n < N) ? W[(size_t)k * N + n] : 0.f;
  }
  __syncthreads();
#pragma unroll
  for (int r = 0; r < 4; ++r) {
    int n = n0 + ty + 8 * r, k = k0 + tx;
    WT[(size_t)n * Kpad + k] = (bf16)tb[tx][ty + 8 * r];
  }
}

// ---------- prep: pack x-even (vectorized), ALL weight transposes, ldj, zero counters ----
// grid: 896 pack blocks + 5056 transpose blocks = 5952
__global__ void prep_k(const float* __restrict__ x, const float* __restrict__ ldj,
                       const float* __restrict__ W_in, const float* __restrict__ W_hid,
                       const float* __restrict__ W_out,
                       bf16* __restrict__ A0, bf16* __restrict__ WT0,
                       bf16* __restrict__ WTh, bf16* __restrict__ WT5,
                       float* __restrict__ y, unsigned* __restrict__ cnt) {
  __shared__ float tb[32][33];
  const int b = blockIdx.x, tid = threadIdx.x;
  if (b < 896) {  // pack: each thread produces 8 consecutive k of one row
    if (b == 0) {
      if (tid == 0) y[(size_t)M_TOT * D_IN] = ldj[0];
      if (tid < 8) cnt[tid] = 0u;   // re-zero barrier counters EVERY launch (ws is poisoned)
    }
    int g = b * 256 + tid;          // 0 .. 229375
    int m = g / 56;                 // 56 groups of 8 cover K0PAD=448
    int kq = g - m * 56, k0 = kq * 8;
    bf16x8 v;
    if (k0 < HALF) {                // kq<=48 -> k0<=384, all 8 k valid (<392)
      const float4* xr = (const float4*)(x + (size_t)m * D_IN + 2 * k0);
      float4 a0 = xr[0], a1 = xr[1], a2 = xr[2], a3 = xr[3];
      v[0] = (bf16)a0.x; v[1] = (bf16)a0.z;
      v[2] = (bf16)a1.x; v[3] = (bf16)a1.z;
      v[4] = (bf16)a2.x; v[5] = (bf16)a2.z;
      v[6] = (bf16)a3.x; v[7] = (bf16)a3.z;
    } else {
#pragma unroll
      for (int j = 0; j < 8; ++j) v[j] = (bf16)0.f;
    }
    *(bf16x8*)(A0 + (size_t)m * K0PAD + k0) = v;
    return;
  }
  int t = b - 896;
  const float* W; bf16* WT; int K, N, Kpad, tn, tk;
  if (t < 448) {                 // W_in: (392 x 1000) -> (1024 x 448)
    W = W_in; WT = WT0; K = HALF; N = MID; Kpad = K0PAD;
    tn = t & 31; tk = t >> 5;
  } else if (t < 4544) {         // W_hid[i]: (1000 x 1000) -> (1024 x 1024)
    int u = t - 448; int i = u >> 10; u &= 1023;
    W = W_hid + (size_t)i * MID * MID; WT = WTh + (size_t)i * NPAD * NPAD;
    K = MID; N = MID; Kpad = NPAD;
    tn = u & 31; tk = u >> 5;
  } else {                       // W_out: (1000 x 392) -> (512 x 1024)
    int u = t - 4544;
    W = W_out; WT = WT5; K = MID; N = HALF; Kpad = NPAD;
    tn = u & 15; tk = u >> 4;
  }
  wtrans_tile(W, WT, K, N, Kpad, tn, tk, tb, tid);
}

// ---------- device-scope grid barrier (one-shot counter per phase) ----------
// Safe-by-construction residency: grid=256 <= capacity 512 (2 blocks/CU at 32KB LDS,
// <=256 VGPR via __launch_bounds__(256,2)). Bounded spin: on pathological stall we
// proceed (test fails loudly) instead of hanging the harness.
__device__ __forceinline__ void gbar(unsigned* c) {
  __syncthreads();  // all block stores drained (compiler emits vmcnt(0) before barrier)
  if (threadIdx.x == 0) {
    __threadfence();  // agent-scope release: prior writes visible device-wide
    __hip_atomic_fetch_add(c, 1u, __ATOMIC_RELEASE, __HIP_MEMORY_SCOPE_AGENT);
    unsigned v = 0u; int it = 0;
    do {
      v = __hip_atomic_load(c, __ATOMIC_ACQUIRE, __HIP_MEMORY_SCOPE_AGENT);
      if (++it > (1 << 22)) break;  // failsafe
      __builtin_amdgcn_s_sleep(8);
    } while (v < (unsigned)NBLK);
    __threadfence();  // acquire side: invalidate stale lines
  }
  __syncthreads();
}

// ---------- GEMM tile: BM x BN, BK=64, 4 waves, XOR-swizzled LDS ----------
// BN=128: waves 2m x 2n, 64x64 per wave (MT=NT=4) -> 0.5 KB LDS/MFMA (balanced vs LDS BW).
// EPI=0: C = relu(A@BT^T + bias) bf16, stride NPAD.
// EPI=1: y pairs: y[m][2n]=x[m][2n]; y[m][2n+1]=x[m][2n+1]+acc+bias[n] (n<HALF)
template <int BM, int BN, int EPI, int K>
__device__ __forceinline__ void mlp_tile(
    const bf16* __restrict__ A, const bf16* __restrict__ BT,
    const float* __restrict__ bias, int bias_n, bf16* __restrict__ C,
    const float* __restrict__ x, float* __restrict__ y,
    bf16* ldsA, bf16* ldsB, int bm, int bn, int tid) {
  constexpr int BK = 64;
  constexpr int MT = BM / 32, NT = BN / 32;
  constexpr int KT = K / BK;
  constexpr int AI = (BM / 4) / 8;   // A g2l16 per wave (8 rows per instr)
  constexpr int BI = (BN / 4) / 8;
  static_assert(K % BK == 0, "K % BK");
  const int wave = tid >> 6, lane = tid & 63;

  // staging: 8 lanes/row, global 16B-chunk XOR-swizzled by row%8, linear LDS dest
  const int srow = lane >> 3;
  const int scol = lane & 7;
  const bf16* gAb = A + ((size_t)bm * BM + wave * (BM / 4)) * K;
  const bf16* gBb = BT + ((size_t)bn * BN + wave * (BN / 4)) * K;
  bf16* lA = &ldsA[wave * (BM / 4) * BK];
  bf16* lB = &ldsB[wave * (BN / 4) * BK];

  const int mlane = lane & 15, quad = lane >> 4;
  const int wm = (wave & 1) * (BM / 2), wn = (wave >> 1) * (BN / 2);
  const int axor = mlane & 7;
  const bf16* raBase = &ldsA[(wm + mlane) * BK];
  const bf16* rbBase = &ldsB[(wn + mlane) * BK];

  f32x4 acc[MT][NT] = {};

  auto stage = [&](int koff) {
#pragma unroll
    for (int i = 0; i < AI; ++i) {
      int r = i * 8 + srow;
      g2l16(gAb + (size_t)r * K + koff + (scol ^ (r & 7)) * 8, lA + i * 8 * BK);
    }
#pragma unroll
    for (int i = 0; i < BI; ++i) {
      int r = i * 8 + srow;
      g2l16(gBb + (size_t)r * K + koff + (scol ^ (r & 7)) * 8, lB + i * 8 * BK);
    }
  };

  stage(0);

  for (int kt = 0; kt < KT; ++kt) {
    __syncthreads();  // staging of tile kt complete
    bf16x8 af[2][MT], bfr[2][NT];
#pragma unroll
    for (int s = 0; s < 2; ++s) {
      const int co = ((s * 4 + quad) ^ axor) * 8;
#pragma unroll
      for (int i = 0; i < MT; ++i) af[s][i] = *(const bf16x8*)(raBase + i * 16 * BK + co);
#pragma unroll
      for (int i = 0; i < NT; ++i) bfr[s][i] = *(const bf16x8*)(rbBase + i * 16 * BK + co);
    }
    __syncthreads();  // all waves done reading LDS
    if (kt + 1 < KT) stage((kt + 1) * BK);
#pragma unroll
    for (int s = 0; s < 2; ++s)
#pragma unroll
      for (int mt = 0; mt < MT; ++mt)
#pragma unroll
        for (int nt = 0; nt < NT; ++nt)
          acc[mt][nt] = __builtin_amdgcn_mfma_f32_16x16x32_bf16(
              af[s][mt], bfr[s][nt], acc[mt][nt], 0, 0, 0);
  }

  const int ng0 = bn * BN + wn + mlane;
  const int mg0 = bm * BM + wm + quad * 4;

  if (EPI == 0) {
    float bv[NT];
#pragma unroll
    for (int nt = 0; nt < NT; ++nt) {
      int n = ng0 + nt * 16;
      bv[nt] = (n < bias_n) ? bias[n] : 0.f;
    }
#pragma unroll
    for (int mt = 0; mt < MT; ++mt)
#pragma unroll
      for (int nt = 0; nt < NT; ++nt)
#pragma unroll
        for (int r = 0; r < 4; ++r) {
          int m = mg0 + mt * 16 + r;
          int n = ng0 + nt * 16;
          float v = fmaxf(acc[mt][nt][r] + bv[nt], 0.f);
          C[(size_t)m * NPAD + n] = (bf16)v;
        }
  } else {
    const float2* x2 = (const float2*)x;
    float2* y2 = (float2*)y;
#pragma unroll
    for (int nt = 0; nt < NT; ++nt) {
      int n = ng0 + nt * 16;
      if (n < HALF) {
        float bb = bias[n];
#pragma unroll
        for (int mt = 0; mt < MT; ++mt)
#pragma unroll
          for (int r = 0; r < 4; ++r) {
            int m = mg0 + mt * 16 + r;
            size_t off = (size_t)m * (D_IN / 2) + n;
            float2 v = x2[off];
            v.y += acc[mt][nt][r] + bb;
            y2[off] = v;
          }
      }
    }
  }
}

// ---------- persistent MLP: 6 layers, device barrier between; 256 blocks x 256 thr ----
// Every layer = exactly 256 tiles (1/block). XCD-chunked lid: each XCD owns 4 bm-stripes
// across all 8 bn-panels (A-slice 1MB + weights 2MB L2 footprint per XCD per layer).
__global__ __launch_bounds__(256, 2)
void mlp_k(const float* __restrict__ b_in, const float* __restrict__ b_hid,
           const float* __restrict__ b_out,
           const float* __restrict__ x, float* __restrict__ y,
           char* __restrict__ ws) {
  alignas(16) __shared__ bf16 ldsA[128 * 64];
  alignas(16) __shared__ bf16 ldsB[128 * 64];

  bf16* A0  = (bf16*)(ws + OFF_A0);
  bf16* H0  = (bf16*)(ws + OFF_H0);
  bf16* H1  = (bf16*)(ws + OFF_H1);
  bf16* WT0 = (bf16*)(ws + OFF_WT0);
  bf16* WTh = (bf16*)(ws + OFF_WTH);
  bf16* WT5 = (bf16*)(ws + OFF_WT5);
  unsigned* cnt = (unsigned*)(ws + OFF_CNT);
  const size_t WH = (size_t)NPAD * NPAD;

  const int tid = threadIdx.x;
  const int lid = (blockIdx.x & 7) * 32 + (blockIdx.x >> 3);  // XCD-chunked
  const int bm = lid >> 3, bn = lid & 7;   // 32 x 8 tiles (128-wide n) / (64-wide for L5)

  mlp_tile<128, 128, 0, K0PAD>(A0, WT0, b_in, MID, H0, nullptr, nullptr,
                               ldsA, ldsB, bm, bn, tid);
  gbar(cnt + 0);
  mlp_tile<128, 128, 0, NPAD>(H0, WTh + 0 * WH, b_hid + 0 * MID, MID, H1, nullptr, nullptr,
                              ldsA, ldsB, bm, bn, tid);
  gbar(cnt + 1);
  mlp_tile<128, 128, 0, NPAD>(H1, WTh + 1 * WH, b_hid + 1 * MID, MID, H0, nullptr, nullptr,
                              ldsA, ldsB, bm, bn, tid);
  gbar(cnt + 2);
  mlp_tile<128, 128, 0, NPAD>(H0, WTh + 2 * WH, b_hid + 2 * MID, MID, H1, nullptr, nullptr,
                              ldsA, ldsB, bm, bn, tid);
  gbar(cnt + 3);
  mlp_tile<128, 128, 0, NPAD>(H1, WTh + 3 * WH, b_hid + 3 * MID, MID, H0, nullptr, nullptr,
                              ldsA, ldsB, bm, bn, tid);
  gbar(cnt + 4);
  // final: 128x64 tiles (32 x 8 over N=512), writes BOTH interleaved columns of y
  mlp_tile<128, 64, 1, NPAD>(H0, WT5, b_out, HALF, nullptr, x, y,
                             ldsA, ldsB, bm, bn, tid);
}

extern "C" void kernel_launch(void* const* d_in, const int* in_sizes, int n_in,
                              void* d_out, int out_size, void* d_ws, size_t ws_size,
                              hipStream_t stream) {
  const float* x     = (const float*)d_in[0];
  const float* ldj   = (const float*)d_in[1];
  const float* W_in  = (const float*)d_in[2];
  const float* b_in  = (const float*)d_in[3];
  const float* W_hid = (const float*)d_in[4];
  const float* b_hid = (const float*)d_in[5];
  const float* W_out = (const float*)d_in[6];
  const float* b_out = (const float*)d_in[7];
  float* y = (float*)d_out;
  char* p = (char*)d_ws;

  bf16* A0  = (bf16*)(p + OFF_A0);
  bf16* WT0 = (bf16*)(p + OFF_WT0);
  bf16* WTh = (bf16*)(p + OFF_WTH);
  bf16* WT5 = (bf16*)(p + OFF_WT5);
  unsigned* cnt = (unsigned*)(p + OFF_CNT);

  // prep: pack + all transposes + ldj + zero barrier counters (1 dispatch)
  prep_k<<<dim3(896 + 5056), 256, 0, stream>>>(x, ldj, W_in, W_hid, W_out,
                                               A0, WT0, WTh, WT5, y, cnt);
  // persistent fused MLP (2nd and final dispatch)
  mlp_k<<<dim3(NBLK), 256, 0, stream>>>(b_in, b_hid, b_out, x, y, p);
}

// Round 5
// 170.494 us; speedup vs baseline: 2.2182x; 2.2182x over previous
//
#include <hip/hip_runtime.h>

typedef __bf16 bf16;
typedef __bf16 bf16x8 __attribute__((ext_vector_type(8)));
typedef float f32x4 __attribute__((ext_vector_type(4)));

#define M_TOT 4096
#define D_IN  784
#define HALF  392
#define MID   1000
#define K0PAD 448   // 392 -> mult of 64
#define NPAD  1024  // 1000 padded

// ---------- async global->LDS 16B ----------
__device__ __forceinline__ void g2l16(const bf16* g, bf16* l) {
  __builtin_amdgcn_global_load_lds(
      (__attribute__((address_space(1))) void*)(g),
      (__attribute__((address_space(3))) void*)(l),
      16, 0, 0);
}

// ---------- 32x32 weight-transpose tile: W (KxN f32) -> WT (Npad x Kpad bf16) ----------
__device__ __forceinline__ void wtrans_tile(const float* __restrict__ W, bf16* __restrict__ WT,
                                            int K, int N, int Kpad, int tn, int tk,
                                            float (*tb)[33], int tid) {
  int n0 = tn * 32, k0 = tk * 32;
  int tx = tid & 31, ty = tid >> 5;
#pragma unroll
  for (int r = 0; r < 4; ++r) {
    int k = k0 + ty + 8 * r, n = n0 + tx;
    tb[ty + 8 * r][tx] = (k < K && n < N) ? W[(size_t)k * N + n] : 0.f;
  }
  __syncthreads();
#pragma unroll
  for (int r = 0; r < 4; ++r) {
    int n = n0 + ty + 8 * r, k = k0 + tx;
    WT[(size_t)n * Kpad + k] = (bf16)tb[tx][ty + 8 * r];
  }
}

// ---------- prep: vectorized pack x-even -> A0 (bf16), W_in transpose, ldj ----------
// grid: 896 pack blocks + 448 WT0 blocks = 1344
__global__ void prep_k(const float* __restrict__ x, const float* __restrict__ ldj,
                       const float* __restrict__ W_in,
                       bf16* __restrict__ A0, bf16* __restrict__ WT0,
                       float* __restrict__ y) {
  __shared__ float tb[32][33];
  const int b = blockIdx.x, tid = threadIdx.x;
  if (b < 896) {  // pack: each thread produces 8 consecutive k of one row
    int g = b * 256 + tid;          // 0 .. 229375
    int m = g / 56;                 // 56 groups of 8 cover K0PAD=448
    int kq = g - m * 56, k0 = kq * 8;
    bf16x8 v;
    if (k0 < HALF) {                // kq<=48 -> k0<=384, all 8 k valid (<392)
      const float4* xr = (const float4*)(x + (size_t)m * D_IN + 2 * k0);
      float4 a0 = xr[0], a1 = xr[1], a2 = xr[2], a3 = xr[3];
      v[0] = (bf16)a0.x; v[1] = (bf16)a0.z;
      v[2] = (bf16)a1.x; v[3] = (bf16)a1.z;
      v[4] = (bf16)a2.x; v[5] = (bf16)a2.z;
      v[6] = (bf16)a3.x; v[7] = (bf16)a3.z;
    } else {
#pragma unroll
      for (int j = 0; j < 8; ++j) v[j] = (bf16)0.f;
    }
    *(bf16x8*)(A0 + (size_t)m * K0PAD + k0) = v;
    if (b == 0 && tid == 0) y[(size_t)M_TOT * D_IN] = ldj[0];
    return;
  }
  // W_in: (392 x 1000) -> WT0 (1024 x 448)
  int u = b - 896;
  wtrans_tile(W_in, WT0, HALF, MID, K0PAD, u & 31, u >> 5, tb, tid);
}

// ---------- GEMM: BM x BN tile, BK=64, 4 waves, double-buffered LDS, counted vmcnt ----
// Pipeline per K-step (T3/T4-minimum): vmcnt(LPS) [tile kt landed, kt+1 in flight]
//   -> raw s_barrier -> ds_read frags -> lgkmcnt(0) -> raw s_barrier
//   -> stage(kt+2 -> buf kt&1) -> MFMA.   Never vmcnt(0) except last iter.
// Swizzle: LDS[row][chunk] holds global chunk (chunk ^ (row&7)); staged via
// pre-swizzled global source (linear LDS dest), read with matching XOR.
// Carried blocks (id >= nb) transpose the NEXT dispatch's B operand.
// EPI=0: C = relu(A@BT^T + bias) bf16, stride NPAD.
// EPI=1: y pairs: y[m][2n]=x[m][2n]; y[m][2n+1]=x[m][2n+1]+acc+bias[n] (n<HALF)
template <int BM, int BN, int EPI, int K>
__global__ __launch_bounds__(256, 2)
void gemm_k(const bf16* __restrict__ A, const bf16* __restrict__ BT,
            const float* __restrict__ bias, int bias_n,
            bf16* __restrict__ C,
            const float* __restrict__ x, float* __restrict__ y, int nb,
            const float* __restrict__ Wx, bf16* __restrict__ WTx,
            int wK, int wN, int wKpad, int wTN) {
  constexpr int BK = 64;
  constexpr int MT = BM / 32, NT = BN / 32;   // 16x16 frags per wave (m, n)
  constexpr int KT = K / BK;
  constexpr int NBM = M_TOT / BM;
  constexpr int AI = (BM / 4) / 8;            // A g2l16 per wave per stage
  constexpr int BI = (BN / 4) / 8;            // B g2l16 per wave per stage
  constexpr int LPS = AI + BI;                // loads per stage per wave
  static_assert(K % BK == 0 && KT >= 2, "K/BK");
  alignas(16) __shared__ bf16 ldsA[2][BM * BK];
  alignas(16) __shared__ bf16 ldsB[2][BN * BK];
  const int tid = threadIdx.x;
  const int id = blockIdx.x;

  if (id >= nb) {  // carried transpose for next dispatch
    int u = id - nb;
    wtrans_tile(Wx, WTx, wK, wN, wKpad, u % wTN, u / wTN, (float(*)[33])&ldsA[0][0], tid);
    return;
  }

  const int wave = tid >> 6, lane = tid & 63;
  const int bm = id % NBM, bn = id / NBM;

  // staging: 8 lanes/row, global 16B-chunk XOR-swizzled by row%8, linear LDS dest
  const int srow = lane >> 3;
  const int scol = lane & 7;
  const bf16* gAb = A + ((size_t)bm * BM + wave * (BM / 4)) * K;
  const bf16* gBb = BT + ((size_t)bn * BN + wave * (BN / 4)) * K;
  const int lAo = wave * (BM / 4) * BK;
  const int lBo = wave * (BN / 4) * BK;

  const int mlane = lane & 15, quad = lane >> 4;
  const int wm = (wave & 1) * (BM / 2), wn = (wave >> 1) * (BN / 2);
  const int axor = mlane & 7;

  auto stage = [&](int kt, int pb) {
    const int koff = kt * BK;
#pragma unroll
    for (int i = 0; i < AI; ++i) {
      int r = i * 8 + srow;
      g2l16(gAb + (size_t)r * K + koff + (scol ^ (r & 7)) * 8,
            &ldsA[pb][lAo + i * 8 * BK]);
    }
#pragma unroll
    for (int i = 0; i < BI; ++i) {
      int r = i * 8 + srow;
      g2l16(gBb + (size_t)r * K + koff + (scol ^ (r & 7)) * 8,
            &ldsB[pb][lBo + i * 8 * BK]);
    }
  };

  f32x4 acc[MT][NT] = {};

  stage(0, 0);
  stage(1, 1);

  for (int kt = 0; kt < KT; ++kt) {
    const int pb = kt & 1;
    // tile kt landed (oldest LPS); tile kt+1's LPS may remain in flight
    if (kt + 1 < KT)
      asm volatile("s_waitcnt vmcnt(%0)" ::"n"(LPS) : "memory");
    else
      asm volatile("s_waitcnt vmcnt(0)" ::: "memory");
    __builtin_amdgcn_s_barrier();            // all waves' tile-kt staging landed
    __builtin_amdgcn_sched_barrier(0);       // pin: no ds_read hoisted above barrier

    const bf16* raB = &ldsA[pb][(wm + mlane) * BK];
    const bf16* rbB = &ldsB[pb][(wn + mlane) * BK];
    bf16x8 af[2][MT], bfr[2][NT];
#pragma unroll
    for (int s = 0; s < 2; ++s) {
      const int co = ((s * 4 + quad) ^ axor) * 8;
#pragma unroll
      for (int i = 0; i < MT; ++i) af[s][i] = *(const bf16x8*)(raB + i * 16 * BK + co);
#pragma unroll
      for (int i = 0; i < NT; ++i) bfr[s][i] = *(const bf16x8*)(rbB + i * 16 * BK + co);
    }
    asm volatile("s_waitcnt lgkmcnt(0)" ::: "memory");  // frags in regs
    __builtin_amdgcn_sched_barrier(0);
    __builtin_amdgcn_s_barrier();            // all waves done reading buf pb
    __builtin_amdgcn_sched_barrier(0);

    if (kt + 2 < KT) stage(kt + 2, pb);      // overwrite buf pb (safe post-barrier)

#pragma unroll
    for (int s = 0; s < 2; ++s)
#pragma unroll
      for (int mt = 0; mt < MT; ++mt)
#pragma unroll
        for (int nt = 0; nt < NT; ++nt)
          acc[mt][nt] = __builtin_amdgcn_mfma_f32_16x16x32_bf16(
              af[s][mt], bfr[s][nt], acc[mt][nt], 0, 0, 0);
  }

  const int ng0 = bn * BN + wn + mlane;
  const int mg0 = bm * BM + wm + quad * 4;

  if (EPI == 0) {
    float bv[NT];
#pragma unroll
    for (int nt = 0; nt < NT; ++nt) {
      int n = ng0 + nt * 16;
      bv[nt] = (n < bias_n) ? bias[n] : 0.f;
    }
#pragma unroll
    for (int mt = 0; mt < MT; ++mt)
#pragma unroll
      for (int nt = 0; nt < NT; ++nt)
#pragma unroll
        for (int r = 0; r < 4; ++r) {
          int m = mg0 + mt * 16 + r;
          int n = ng0 + nt * 16;
          float v = fmaxf(acc[mt][nt][r] + bv[nt], 0.f);
          C[(size_t)m * NPAD + n] = (bf16)v;
        }
  } else {
    const float2* x2 = (const float2*)x;
    float2* y2 = (float2*)y;
#pragma unroll
    for (int nt = 0; nt < NT; ++nt) {
      int n = ng0 + nt * 16;
      if (n < HALF) {
        float bb = bias[n];
#pragma unroll
        for (int mt = 0; mt < MT; ++mt)
#pragma unroll
          for (int r = 0; r < 4; ++r) {
            int m = mg0 + mt * 16 + r;
            size_t off = (size_t)m * (D_IN / 2) + n;
            float2 v = x2[off];
            v.y += acc[mt][nt][r] + bb;
            y2[off] = v;
          }
      }
    }
  }
}

extern "C" void kernel_launch(void* const* d_in, const int* in_sizes, int n_in,
                              void* d_out, int out_size, void* d_ws, size_t ws_size,
                              hipStream_t stream) {
  const float* x     = (const float*)d_in[0];
  const float* ldj   = (const float*)d_in[1];
  const float* W_in  = (const float*)d_in[2];
  const float* b_in  = (const float*)d_in[3];
  const float* W_hid = (const float*)d_in[4];
  const float* b_hid = (const float*)d_in[5];
  const float* W_out = (const float*)d_in[6];
  const float* b_out = (const float*)d_in[7];
  float* y = (float*)d_out;

  // workspace layout (bytes, 256-aligned)
  char* p = (char*)d_ws;
  bf16* A0  = (bf16*)(p + 0);           // 4096 x 448   (3,670,016 B)
  bf16* H0  = (bf16*)(p + 3670016);     // 4096 x 1024  (8,388,608 B)
  bf16* H1  = (bf16*)(p + 12058624);    // 4096 x 1024
  bf16* WT0 = (bf16*)(p + 20447232);    // 1024 x 448   (917,504 B)
  bf16* WTh = (bf16*)(p + 21364736);    // 4 x 1024 x 1024 (8,388,608 B)
  bf16* WT5 = (bf16*)(p + 29753344);    // 512 x 1024   (1,048,576 B)

  const size_t WH = (size_t)NPAD * NPAD;
  const size_t WS = (size_t)MID * MID;

  // --- prep: pack (vectorized) + WT0 only; other transposes ride the GEMM dispatches ---
  prep_k<<<dim3(896 + 448), 256, 0, stream>>>(x, ldj, W_in, A0, WT0, y);

  // --- MLP: 6 GEMMs, 128x64 tiles, dbuf+counted-vmcnt pipeline, 512 blocks (2/CU).
  //     Dispatch i carries the transpose whose result is needed by dispatch i+1. ---
  gemm_k<128, 64, 0, K0PAD><<<dim3(512 + 1024), 256, 0, stream>>>(
      A0, WT0, b_in, MID, H0, nullptr, nullptr, 512,
      W_hid + 0 * WS, WTh + 0 * WH, MID, MID, NPAD, 32);
  gemm_k<128, 64, 0, NPAD><<<dim3(512 + 1024), 256, 0, stream>>>(
      H0, WTh + 0 * WH, b_hid + 0 * MID, MID, H1, nullptr, nullptr, 512,
      W_hid + 1 * WS, WTh + 1 * WH, MID, MID, NPAD, 32);
  gemm_k<128, 64, 0, NPAD><<<dim3(512 + 1024), 256, 0, stream>>>(
      H1, WTh + 1 * WH, b_hid + 1 * MID, MID, H0, nullptr, nullptr, 512,
      W_hid + 2 * WS, WTh + 2 * WH, MID, MID, NPAD, 32);
  gemm_k<128, 64, 0, NPAD><<<dim3(512 + 1024), 256, 0, stream>>>(
      H0, WTh + 2 * WH, b_hid + 2 * MID, MID, H1, nullptr, nullptr, 512,
      W_hid + 3 * WS, WTh + 3 * WH, MID, MID, NPAD, 32);
  gemm_k<128, 64, 0, NPAD><<<dim3(512 + 512), 256, 0, stream>>>(
      H1, WTh + 3 * WH, b_hid + 3 * MID, MID, H0, nullptr, nullptr, 512,
      W_out, WT5, MID, HALF, NPAD, 16);
  // final: writes BOTH interleaved columns (even = copy of x, odd = second + shift)
  gemm_k<64, 64, 1, NPAD><<<dim3(512), 256, 0, stream>>>(
      H0, WT5, b_out, HALF, nullptr, x, y, 512,
      nullptr, nullptr, 0, 0, 0, 1);
}